// Round 8
// baseline (426.053 us; speedup 1.0000x reference)
//
#include <hip/hip_runtime.h>
#include <hip/hip_bf16.h>

#define NDIM 512
#define NN   (NDIM * NDIM)

// Workspace:
//   bf16 planes 0..127   : g hi, channel c.  c<64: [i][k]=g[i][k][c]; c>=64: [i][k]=g[k][i][c]
//   bf16 planes 128..255 : g lo, same indexing.              (128 MiB)
//   fp32 planes @ 256*NN*2 B: t[dd][i][j], 64 planes          (64 MiB)
// Transient: wt1+cb1 at wst start (einsum overwrites later);
//            wt2+cb2 at wsg start (written after einsum consumes g).
// LN is FOLDED into the GEMMs: out = rstd*(acc - mu*c1) + c2, W' = ln_w*W,
// c1[o] = sum_k ln_w[k]W[k][o], c2[o] = sum_k ln_b[k]W[k][o] + bias[o].

using short8 = __attribute__((ext_vector_type(8))) short;
using f32x4  = __attribute__((ext_vector_type(4))) float;
typedef unsigned int uint32;
typedef unsigned short ushort;

__device__ __forceinline__ float sigmoidf_(float z) { return 1.f / (1.f + __expf(-z)); }
__device__ __forceinline__ uint32 pkbf2(float a, float b) {
    __hip_bfloat162 h = __float22bfloat162_rn(float2{a, b});
    uint32 u; __builtin_memcpy(&u, &h, 4); return u;
}
__device__ __forceinline__ ushort bfbits(float f) {
    __hip_bfloat16 h = __float2bfloat16(f);
    ushort u; __builtin_memcpy(&u, &h, 2); return u;
}
__device__ __forceinline__ float bf2f(ushort h) {
    return __uint_as_float(((uint32)h) << 16);
}

// ---------------------------------------------------------------------------
// Weight prep: W'[k][o] = ln_w[k]*W[k][o], bf16 hi/lo, rows interleaved in
// 16-groups (s<8: P ch 8q+s, s>=8: G ch 8q+s-8). hi[(h*128+row)*K+k], lo +256*K.
// ---------------------------------------------------------------------------
__global__ void k_prep(const float* __restrict__ Wp, const float* __restrict__ Wg,
                       const float* __restrict__ lnw, int K,
                       ushort* __restrict__ dst)
{
    const int idx = blockIdx.x * 256 + threadIdx.x;   // 0 .. K*128-1
    const int k = idx >> 7, o = idx & 127;
    const int h = o >> 6, cl = o & 63;
    const int q = cl >> 3, s7 = cl & 7;
    const float wk = lnw[k];
    const float vp = Wp[k * 128 + o] * wk;
    const float vg = Wg[k * 128 + o] * wk;
    const int rowp = (q << 4) + s7;
    const int rowg = (q << 4) + 8 + s7;
    ushort hi;
    hi = bfbits(vp);
    dst[(h * 128 + rowp) * K + k] = hi;
    dst[256 * K + (h * 128 + rowp) * K + k] = bfbits(vp - bf2f(hi));
    hi = bfbits(vg);
    dst[(h * 128 + rowg) * K + k] = hi;
    dst[256 * K + (h * 128 + rowg) * K + k] = bfbits(vg - bf2f(hi));
}

// cb layout: [0..127]=c1P, [128..255]=c2P+biasP, [256..383]=c1G, [384..511]=c2G+biasG
__global__ void k_csum(const float* __restrict__ Wp, const float* __restrict__ Wg,
                       const float* __restrict__ lnw, const float* __restrict__ lnb,
                       const float* __restrict__ bp, const float* __restrict__ bg,
                       int K, float* __restrict__ cb)
{
    const int tid = threadIdx.x;
    const int o = tid & 127;
    const float* W = (tid < 128) ? Wp : Wg;
    const float* bias = (tid < 128) ? bp : bg;
    float c1 = 0.f, c2 = 0.f;
    for (int k = 0; k < K; ++k) {
        const float wv = W[k * 128 + o];
        c1 = fmaf(lnw[k], wv, c1);
        c2 = fmaf(lnb[k], wv, c2);
    }
    const int base = (tid < 128) ? 0 : 256;
    cb[base + o] = c1;
    cb[base + 128 + o] = c2 + bias[o];
}

// ---------------------------------------------------------------------------
// Stage 1: cast-x GEMM (pi,gi interleaved), LN folded into epilogue.
// ---------------------------------------------------------------------------
__global__ __launch_bounds__(256, 4)
void k_stage1(const float* __restrict__ x, const float* __restrict__ mask,
              const ushort* __restrict__ wt1, const float* __restrict__ cb,
              ushort* __restrict__ wsg)
{
    __shared__ char sbuf[32768];   // A tile bf16(x) swz; later G u32-packed
    __shared__ float Ms[128], Mu[128], Rs[128];

    const int tid = threadIdx.x;
    const int bx = blockIdx.x;
    const int y  = blockIdx.y;
    const int o0 = y * 64;

    long posBase, outBase; int stride;
    if (y == 0) {
        posBase = ((long)(bx >> 2)) * 512 + (long)(bx & 3) * 128;
        outBase = posBase; stride = 1;
    } else {
        posBase = ((long)(bx >> 9)) * 65536 + (bx & 511);
        outBase = (long)(bx & 511) * 512 + ((bx >> 9) * 128);
        stride = 512;
    }

    // --- load x, cast to bf16 A tile, one-pass stats ---
    {
        const int r = tid >> 1, hf = tid & 1;
        const float* xr = x + (posBase + (long)r * stride) * 128 + hf * 64;
        float s = 0.f, ss = 0.f;
#pragma unroll
        for (int q = 0; q < 8; ++q) {
            const float4 a = ((const float4*)xr)[2*q];
            const float4 b = ((const float4*)xr)[2*q+1];
            s  += a.x + a.y + a.z + a.w + b.x + b.y + b.z + b.w;
            ss = fmaf(a.x,a.x, fmaf(a.y,a.y, fmaf(a.z,a.z, fmaf(a.w,a.w, ss))));
            ss = fmaf(b.x,b.x, fmaf(b.y,b.y, fmaf(b.z,b.z, fmaf(b.w,b.w, ss))));
            uint4 pk;
            pk.x = pkbf2(a.x, a.y); pk.y = pkbf2(a.z, a.w);
            pk.z = pkbf2(b.x, b.y); pk.w = pkbf2(b.z, b.w);
            const int col = (hf*128 + q*16) ^ ((r & 15) << 4);
            *(uint4*)(sbuf + r*256 + col) = pk;
        }
        s  += __shfl_xor(s, 1);
        ss += __shfl_xor(ss, 1);
        const float mu = s * (1.f/128.f);
        const float var = ss * (1.f/128.f) - mu*mu;
        const float rstd = rsqrtf(var + 1e-5f);
        if (hf == 0) {
            Ms[r] = mask[posBase + (long)r * stride];
            Mu[r] = mu; Rs[r] = rstd;
        }
    }
    __syncthreads();

    const int w = tid >> 6, l = tid & 63;
    const int mrow = (w & 1) * 64, ncol = (w >> 1) * 64;

    f32x4 acc[4][4];
#pragma unroll
    for (int m = 0; m < 4; ++m)
#pragma unroll
        for (int n = 0; n < 4; ++n) acc[m][n] = (f32x4){0.f,0.f,0.f,0.f};

#pragma unroll
    for (int step = 0; step < 4; ++step) {
        short8 ah[4], bh[4], bl[4];
#pragma unroll
        for (int n = 0; n < 4; ++n) {
            const int row = y*128 + ncol + n*16 + (l & 15);
            const int idx = row*128 + step*32 + (l >> 4)*8;
            bh[n] = *(const short8*)(wt1 + idx);
            bl[n] = *(const short8*)(wt1 + 32768 + idx);
        }
#pragma unroll
        for (int m = 0; m < 4; ++m) {
            const int pos = mrow + m*16 + (l & 15);
            const int col = (step*64 + (l >> 4)*16) ^ ((pos & 15) << 4);
            ah[m] = *(const short8*)(sbuf + pos*256 + col);
        }
#pragma unroll
        for (int m = 0; m < 4; ++m) {
#pragma unroll
            for (int n = 0; n < 4; ++n) {
                acc[m][n] = __builtin_amdgcn_mfma_f32_16x16x32_bf16(ah[m], bh[n], acc[m][n], 0, 0, 0);
                acc[m][n] = __builtin_amdgcn_mfma_f32_16x16x32_bf16(ah[m], bl[n], acc[m][n], 0, 0, 0);
            }
        }
    }
    __syncthreads();   // A reads done; sbuf becomes G (u32-packed hi/lo)

    // --- LN-folded gate, all lanes active (j<8: e 0,1; j>=8: e 2,3) ---
    const int j = l & 15;
    const int e0 = (j >= 8) ? 2 : 0;
#pragma unroll
    for (int m = 0; m < 4; ++m) {
#pragma unroll
        for (int n = 0; n < 4; ++n) {
            const f32x4 a = acc[m][n];
            float pr[4];
#pragma unroll
            for (int e = 0; e < 4; ++e) pr[e] = __shfl_xor(a[e], 8);
            const int cl = (w >> 1)*32 + n*8 + (j & 7);
            const int och = o0 + cl;
            const float c1p = cb[och],       c2p = cb[128 + och];
            const float c1g = cb[256 + och], c2g = cb[384 + och];
            const int p0 = mrow + m*16 + (l >> 4)*4;
            uint2 pk;
#pragma unroll
            for (int t = 0; t < 2; ++t) {
                const int e = e0 + t;
                const float accP = (j >= 8) ? pr[e] : a[e];
                const float accG = (j >= 8) ? a[e] : pr[e];
                const float mu = Mu[p0+e], rstd = Rs[p0+e];
                const float p_ = fmaf(rstd, accP - mu*c1p, c2p);
                const float g_ = fmaf(rstd, accG - mu*c1g, c2g);
                const float g = p_ * sigmoidf_(g_) * Ms[p0+e];
                const ushort hi = bfbits(g);
                const ushort lo = bfbits(g - bf2f(hi));
                ((uint32*)&pk)[t] = ((uint32)hi << 16) | (uint32)lo;
            }
            *(uint2*)(sbuf + cl*512 + ((p0*4) ^ ((cl & 7) << 4)) + e0*4) = pk;
        }
    }
    __syncthreads();

    // --- cooperative plane stores: 256B-contiguous runs per plane ---
#pragma unroll
    for (int it = 0; it < 2; ++it) {
        const int u = it*256 + tid;
        const int c = u >> 3, seg = u & 7;
        ushort* hd = wsg + (long)(o0 + c) * NN + outBase + seg*16;
        ushort* ld = wsg + (long)(128 + o0 + c) * NN + outBase + seg*16;
#pragma unroll
        for (int half = 0; half < 2; ++half) {
            short8 hv, lv;
#pragma unroll
            for (int q = 0; q < 2; ++q) {
                const int b = seg*64 + half*32 + q*16;
                const uint4 w4 = *(const uint4*)(sbuf + c*512 + (b ^ ((c & 7) << 4)));
                hv[q*4+0] = (short)(w4.x >> 16); lv[q*4+0] = (short)(w4.x & 0xffffu);
                hv[q*4+1] = (short)(w4.y >> 16); lv[q*4+1] = (short)(w4.y & 0xffffu);
                hv[q*4+2] = (short)(w4.z >> 16); lv[q*4+2] = (short)(w4.z & 0xffffu);
                hv[q*4+3] = (short)(w4.w >> 16); lv[q*4+3] = (short)(w4.w & 0xffffu);
            }
            *(short8*)(hd + half*8) = hv;
            *(short8*)(ld + half*8) = lv;
        }
    }
}

// ---------------------------------------------------------------------------
// Triangular einsums (unchanged): 64 NT-GEMMs, bf16 hi/lo (3 products), MFMA.
// ---------------------------------------------------------------------------
__global__ __launch_bounds__(256, 2)
void k_einsum(const ushort* __restrict__ wsg, float* __restrict__ wst)
{
    const int bid = blockIdx.x;
    const int nb  = (bid & 7) * 128 + (bid >> 3);
    const int ch  = nb >> 4;
    const int bi  = (nb >> 2) & 3, bj = nb & 3;
    const int pch = (ch < 32) ? ch : ch + 32;

    const ushort* __restrict__ PH = wsg + (long)pch * NN;
    const ushort* __restrict__ PL = wsg + (long)(128 + pch) * NN;
    const ushort* __restrict__ QH = wsg + (long)(pch + 32) * NN;
    const ushort* __restrict__ QL = wsg + (long)(128 + pch + 32) * NN;
    float* __restrict__ T = wst + (long)ch * NN;

    __shared__ ushort smem[4 * 8192];

    const int tid = threadIdx.x;
    const int w = tid >> 6, l = tid & 63;

    int ebase[4];
#pragma unroll
    for (int jq = 0; jq < 4; ++jq) {
        const int ci  = w * 256 + jq * 64 + l;
        const int row = ci >> 3, cs = ci & 7;
        ebase[jq] = row * 512 + ((cs ^ (row & 7)) << 3);
    }
    const int aOff = bi * 128 * 512;
    const int bOff = bj * 128 * 512;

    f32x4 acc[4][4];
#pragma unroll
    for (int m = 0; m < 4; ++m)
#pragma unroll
        for (int n = 0; n < 4; ++n) acc[m][n] = (f32x4){0.f, 0.f, 0.f, 0.f};

    const int mrow = (w & 1) * 64;
    const int ncol = (w >> 1) * 64;

    for (int step = 0; step < 8; ++step) {
        __syncthreads();
        const int kOff = step * 64;
#pragma unroll
        for (int jq = 0; jq < 4; ++jq) {
            char* dst = (char*)smem + (w * 256 + jq * 64) * 16;
            const ushort* sa_h = PH + aOff + ebase[jq] + kOff;
            const ushort* sa_l = PL + aOff + ebase[jq] + kOff;
            const ushort* sb_h = QH + bOff + ebase[jq] + kOff;
            const ushort* sb_l = QL + bOff + ebase[jq] + kOff;
            __builtin_amdgcn_global_load_lds((const __attribute__((address_space(1))) void*)sa_h,
                (__attribute__((address_space(3))) void*)(dst), 16, 0, 0);
            __builtin_amdgcn_global_load_lds((const __attribute__((address_space(1))) void*)sa_l,
                (__attribute__((address_space(3))) void*)(dst + 16384), 16, 0, 0);
            __builtin_amdgcn_global_load_lds((const __attribute__((address_space(1))) void*)sb_h,
                (__attribute__((address_space(3))) void*)(dst + 32768), 16, 0, 0);
            __builtin_amdgcn_global_load_lds((const __attribute__((address_space(1))) void*)sb_l,
                (__attribute__((address_space(3))) void*)(dst + 49152), 16, 0, 0);
        }
        __syncthreads();

#pragma unroll
        for (int ks = 0; ks < 2; ++ks) {
            short8 ah[4], al[4], bh[4], bl[4];
#pragma unroll
            for (int m = 0; m < 4; ++m) {
                const int r = mrow + m * 16 + (l & 15);
                const int off = r * 128 + ((((ks << 2) + (l >> 4)) ^ (r & 7)) << 4);
                ah[m] = *(const short8*)((const char*)smem + off);
                al[m] = *(const short8*)((const char*)smem + 16384 + off);
            }
#pragma unroll
            for (int n = 0; n < 4; ++n) {
                const int r = ncol + n * 16 + (l & 15);
                const int off = r * 128 + ((((ks << 2) + (l >> 4)) ^ (r & 7)) << 4);
                bh[n] = *(const short8*)((const char*)smem + 32768 + off);
                bl[n] = *(const short8*)((const char*)smem + 49152 + off);
            }
#pragma unroll
            for (int m = 0; m < 4; ++m) {
#pragma unroll
                for (int n = 0; n < 4; ++n) {
                    acc[m][n] = __builtin_amdgcn_mfma_f32_16x16x32_bf16(ah[m], bh[n], acc[m][n], 0, 0, 0);
                    acc[m][n] = __builtin_amdgcn_mfma_f32_16x16x32_bf16(ah[m], bl[n], acc[m][n], 0, 0, 0);
                    acc[m][n] = __builtin_amdgcn_mfma_f32_16x16x32_bf16(al[m], bh[n], acc[m][n], 0, 0, 0);
                }
            }
        }
    }

    const int rbase = bi * 128 + mrow;
    const int cbase = bj * 128 + ncol;
#pragma unroll
    for (int m = 0; m < 4; ++m) {
#pragma unroll
        for (int n = 0; n < 4; ++n) {
#pragma unroll
            for (int r = 0; r < 4; ++r) {
                const int row = rbase + m * 16 + (l >> 4) * 4 + r;
                const int col = cbase + n * 16 + (l & 15);
                T[(long)row * NDIM + col] = acc[m][n][r];
            }
        }
    }
}

// ---------------------------------------------------------------------------
// Stage 2: gather t planes, LN2-folded dual GEMM (po,go), gate, mask -> out.
// ---------------------------------------------------------------------------
__global__ __launch_bounds__(256, 3)
void k_stage2(const float* __restrict__ wst, const float* __restrict__ mask,
              const ushort* __restrict__ wt2, const float* __restrict__ cb,
              float* __restrict__ out)
{
    __shared__ float tP[128][65];   // t gather; later reused as O[pos][ch]
    __shared__ char abuf[16384];    // A tile [128 pos][64 ch] bf16 swz
    __shared__ float Ms[128], Mu[128], Rs[128];

    const int tid = threadIdx.x;
    const long pos0 = (long)blockIdx.x * 128;
    const int y = blockIdx.y;
    const int o0 = y * 64;

#pragma unroll
    for (int q = 0; q < 8; ++q) {
        const int u = q*256 + tid, d = u >> 5, p4 = u & 31;
        const float4 v = *(const float4*)(wst + (long)d * NN + pos0 + p4*4);
        tP[p4*4+0][d] = v.x; tP[p4*4+1][d] = v.y;
        tP[p4*4+2][d] = v.z; tP[p4*4+3][d] = v.w;
    }
    if (tid < 128) Ms[tid] = mask[pos0 + tid];
    __syncthreads();

    // stats + direct bf16 cast (LN folded into epilogue)
    {
        const int r = tid >> 1, hf = tid & 1;
        float v[32]; float s = 0.f, ss = 0.f;
#pragma unroll
        for (int jz = 0; jz < 32; ++jz) {
            v[jz] = tP[r][hf*32+jz];
            s += v[jz]; ss = fmaf(v[jz], v[jz], ss);
        }
        s  += __shfl_xor(s, 1);
        ss += __shfl_xor(ss, 1);
        const float mu = s * (1.f/64.f);
        const float var = ss * (1.f/64.f) - mu*mu;
        const float rstd = rsqrtf(var + 1e-5f);
        if (hf == 0) { Mu[r] = mu; Rs[r] = rstd; }
#pragma unroll
        for (int jj = 0; jj < 4; ++jj) {
            uint4 pk;
            pk.x = pkbf2(v[jj*8+0], v[jj*8+1]); pk.y = pkbf2(v[jj*8+2], v[jj*8+3]);
            pk.z = pkbf2(v[jj*8+4], v[jj*8+5]); pk.w = pkbf2(v[jj*8+6], v[jj*8+7]);
            const int col = (hf*64 + jj*16) ^ ((r & 7) << 4);
            *(uint4*)(abuf + r*128 + col) = pk;
        }
    }
    __syncthreads();

    const int w = tid >> 6, l = tid & 63;
    const int mrow = (w & 1) * 64, ncol = (w >> 1) * 64;

    f32x4 acc[4][4];
#pragma unroll
    for (int m = 0; m < 4; ++m)
#pragma unroll
        for (int n = 0; n < 4; ++n) acc[m][n] = (f32x4){0.f,0.f,0.f,0.f};

#pragma unroll
    for (int step = 0; step < 2; ++step) {
        short8 ah[4], bh[4], bl[4];
#pragma unroll
        for (int n = 0; n < 4; ++n) {
            const int row = y*128 + ncol + n*16 + (l & 15);
            const int idx = row*64 + step*32 + (l >> 4)*8;
            bh[n] = *(const short8*)(wt2 + idx);
            bl[n] = *(const short8*)(wt2 + 16384 + idx);
        }
#pragma unroll
        for (int m = 0; m < 4; ++m) {
            const int pos = mrow + m*16 + (l & 15);
            const int col = (step*64 + (l >> 4)*16) ^ ((pos & 7) << 4);
            ah[m] = *(const short8*)(abuf + pos*128 + col);
        }
#pragma unroll
        for (int m = 0; m < 4; ++m) {
#pragma unroll
            for (int n = 0; n < 4; ++n) {
                acc[m][n] = __builtin_amdgcn_mfma_f32_16x16x32_bf16(ah[m], bh[n], acc[m][n], 0, 0, 0);
                acc[m][n] = __builtin_amdgcn_mfma_f32_16x16x32_bf16(ah[m], bl[n], acc[m][n], 0, 0, 0);
            }
        }
    }

    // LN-folded gate, all lanes active; O[pos][ch] into tP
    const int j = l & 15;
    const int e0 = (j >= 8) ? 2 : 0;
#pragma unroll
    for (int m = 0; m < 4; ++m) {
#pragma unroll
        for (int n = 0; n < 4; ++n) {
            const f32x4 a = acc[m][n];
            float pr[4];
#pragma unroll
            for (int e = 0; e < 4; ++e) pr[e] = __shfl_xor(a[e], 8);
            const int cl = (w >> 1)*32 + n*8 + (j & 7);
            const int och = o0 + cl;
            const float c1p = cb[och],       c2p = cb[128 + och];
            const float c1g = cb[256 + och], c2g = cb[384 + och];
            const int p0 = mrow + m*16 + (l >> 4)*4;
#pragma unroll
            for (int t = 0; t < 2; ++t) {
                const int e = e0 + t;
                const float accP = (j >= 8) ? pr[e] : a[e];
                const float accG = (j >= 8) ? a[e] : pr[e];
                const float mu = Mu[p0+e], rstd = Rs[p0+e];
                const float p_ = fmaf(rstd, accP - mu*c1p, c2p);
                const float g_ = fmaf(rstd, accG - mu*c1g, c2g);
                tP[p0 + e][cl] = p_ * sigmoidf_(g_) * Ms[p0+e];
            }
        }
    }
    __syncthreads();

    // cooperative output stores
    {
        const int r2 = tid >> 1, h2 = tid & 1;
        float* op = out + (pos0 + r2)*128 + o0 + h2*32;
#pragma unroll
        for (int i = 0; i < 8; ++i) {
            float4 v;
            v.x = tP[r2][h2*32 + i*4 + 0];
            v.y = tP[r2][h2*32 + i*4 + 1];
            v.z = tP[r2][h2*32 + i*4 + 2];
            v.w = tP[r2][h2*32 + i*4 + 3];
            *(float4*)(op + i*4) = v;
        }
    }
}

// ---------------------------------------------------------------------------
extern "C" void kernel_launch(void* const* d_in, const int* in_sizes, int n_in,
                              void* d_out, int out_size, void* d_ws, size_t ws_size,
                              hipStream_t stream)
{
    const float* x     = (const float*)d_in[0];
    const float* mask  = (const float*)d_in[1];
    const float* ln1_w = (const float*)d_in[2];
    const float* ln1_b = (const float*)d_in[3];
    const float* pi_w  = (const float*)d_in[4];
    const float* pi_b  = (const float*)d_in[5];
    const float* gi_w  = (const float*)d_in[6];
    const float* gi_b  = (const float*)d_in[7];
    const float* ln2_w = (const float*)d_in[8];
    const float* ln2_b = (const float*)d_in[9];
    const float* po_w  = (const float*)d_in[10];
    const float* po_b  = (const float*)d_in[11];
    const float* go_w  = (const float*)d_in[12];
    const float* go_b  = (const float*)d_in[13];

    ushort* wsg = (ushort*)d_ws;                              // 256 bf16 planes
    float* wst = (float*)((char*)d_ws + (long)256 * NN * 2);  // 64 fp32 planes
    ushort* wt1 = (ushort*)wst;                               // 128 KiB transient
    float*  cb1 = (float*)(wt1 + 65536);                      // 2 KiB
    ushort* wt2 = wsg;                                        // 64 KiB transient
    float*  cb2 = (float*)(wt2 + 32768);                      // 2 KiB

    k_prep<<<64, 256, 0, stream>>>(pi_w, gi_w, ln1_w, 128, wt1);
    k_csum<<<1, 256, 0, stream>>>(pi_w, gi_w, ln1_w, ln1_b, pi_b, gi_b, 128, cb1);
    k_stage1<<<dim3(2048, 2), 256, 0, stream>>>(x, mask, wt1, cb1, wsg);
    k_einsum<<<1024, 256, 0, stream>>>(wsg, wst);
    k_prep<<<32, 256, 0, stream>>>(po_w, go_w, ln2_w, 64, wt2);
    k_csum<<<1, 256, 0, stream>>>(po_w, go_w, ln2_w, ln2_b, po_b, go_b, 64, cb2);
    k_stage2<<<dim3(2048, 2), 256, 0, stream>>>(wst, mask, wt2, cb2, (float*)d_out);
}

// Round 9
// 390.370 us; speedup vs baseline: 1.0914x; 1.0914x over previous
//
#include <hip/hip_runtime.h>
#include <hip/hip_bf16.h>

#define NDIM 512
#define NN   (NDIM * NDIM)

// Workspace:
//   bf16 planes 0..127   : g hi, channel c.  c<64: [i][k]=g[i][k][c]; c>=64: [i][k]=g[k][i][c]
//   bf16 planes 128..255 : g lo, same indexing.              (128 MiB)
//   fp32 planes @ 256*NN*2 B: t[dd][i][j], 64 planes          (64 MiB)
// Transient: wt1+cb1 at wst start (einsum overwrites later);
//            wt2+cb2 at wsg start (written after einsum consumes g).
// LN folded into GEMMs: out = rstd*(acc - mu*c1) + c2, W' = ln_w*W.

using short8 = __attribute__((ext_vector_type(8))) short;
using f32x4  = __attribute__((ext_vector_type(4))) float;
typedef unsigned int uint32;
typedef unsigned short ushort;

__device__ __forceinline__ float sigmoidf_(float z) { return 1.f / (1.f + __expf(-z)); }
__device__ __forceinline__ uint32 pkbf2(float a, float b) {
    __hip_bfloat162 h = __float22bfloat162_rn(float2{a, b});
    uint32 u; __builtin_memcpy(&u, &h, 4); return u;
}
__device__ __forceinline__ ushort bfbits(float f) {
    __hip_bfloat16 h = __float2bfloat16(f);
    ushort u; __builtin_memcpy(&u, &h, 2); return u;
}
__device__ __forceinline__ float bf2f(ushort h) {
    return __uint_as_float(((uint32)h) << 16);
}

// ---------------------------------------------------------------------------
// Weight prep: W'[k][o] = ln_w[k]*W[k][o], bf16 hi/lo, rows interleaved in
// 16-groups (s<8: P ch 8q+s, s>=8: G ch 8q+s-8). hi[(h*128+row)*K+k], lo +256*K.
// ---------------------------------------------------------------------------
__global__ void k_prep(const float* __restrict__ Wp, const float* __restrict__ Wg,
                       const float* __restrict__ lnw, int K,
                       ushort* __restrict__ dst)
{
    const int idx = blockIdx.x * 256 + threadIdx.x;   // 0 .. K*128-1
    const int k = idx >> 7, o = idx & 127;
    const int h = o >> 6, cl = o & 63;
    const int q = cl >> 3, s7 = cl & 7;
    const float wk = lnw[k];
    const float vp = Wp[k * 128 + o] * wk;
    const float vg = Wg[k * 128 + o] * wk;
    const int rowp = (q << 4) + s7;
    const int rowg = (q << 4) + 8 + s7;
    ushort hi;
    hi = bfbits(vp);
    dst[(h * 128 + rowp) * K + k] = hi;
    dst[256 * K + (h * 128 + rowp) * K + k] = bfbits(vp - bf2f(hi));
    hi = bfbits(vg);
    dst[(h * 128 + rowg) * K + k] = hi;
    dst[256 * K + (h * 128 + rowg) * K + k] = bfbits(vg - bf2f(hi));
}

// cb: [0..127]=c1P, [128..255]=c2P+biasP, [256..383]=c1G, [384..511]=c2G+biasG
// Grid 2 (block 0: P, block 1: G); k split across thread halves, LDS combine.
__global__ void k_csum(const float* __restrict__ Wp, const float* __restrict__ Wg,
                       const float* __restrict__ lnw, const float* __restrict__ lnb,
                       const float* __restrict__ bp, const float* __restrict__ bg,
                       int K, float* __restrict__ cb)
{
    __shared__ float red[2][2][128];
    const int b = blockIdx.x;
    const float* W = b ? Wg : Wp;
    const float* bias = b ? bg : bp;
    const int tid = threadIdx.x;
    const int o = tid & 127, kh = tid >> 7;
    const int kham = K >> 1;
    const int k0 = kh * kham;
    float c1 = 0.f, c2 = 0.f;
#pragma unroll 8
    for (int k = 0; k < kham; ++k) {
        const float wv = W[(k0 + k) * 128 + o];
        c1 = fmaf(lnw[k0 + k], wv, c1);
        c2 = fmaf(lnb[k0 + k], wv, c2);
    }
    red[kh][0][o] = c1; red[kh][1][o] = c2;
    __syncthreads();
    if (kh == 0) {
        const int base = b ? 256 : 0;
        cb[base + o] = red[0][0][o] + red[1][0][o];
        cb[base + 128 + o] = red[0][1][o] + red[1][1][o] + bias[o];
    }
}

// ---------------------------------------------------------------------------
// Stage 1: cast-x GEMM (pi,gi interleaved), LN folded; B-fragment register
// double-buffer (set step&1), first set issued before the barrier.
// ---------------------------------------------------------------------------
__global__ __launch_bounds__(256, 3)
void k_stage1(const float* __restrict__ x, const float* __restrict__ mask,
              const ushort* __restrict__ wt1, const float* __restrict__ cb,
              ushort* __restrict__ wsg)
{
    __shared__ char sbuf[32768];   // A tile bf16(x) swz; later G u32-packed
    __shared__ float Ms[128], Mu[128], Rs[128];

    const int tid = threadIdx.x;
    const int bx = blockIdx.x;
    const int y  = blockIdx.y;
    const int o0 = y * 64;
    const int w = tid >> 6, l = tid & 63;
    const int mrow = (w & 1) * 64, ncol = (w >> 1) * 64;

    long posBase, outBase; int stride;
    if (y == 0) {
        posBase = ((long)(bx >> 2)) * 512 + (long)(bx & 3) * 128;
        outBase = posBase; stride = 1;
    } else {
        posBase = ((long)(bx >> 9)) * 65536 + (bx & 511);
        outBase = (long)(bx & 511) * 512 + ((bx >> 9) * 128);
        stride = 512;
    }

    // --- B prefetch for step 0 (overlaps x-load/LN; no LDS dependence) ---
    short8 bh[2][4], bl[2][4];
#pragma unroll
    for (int n = 0; n < 4; ++n) {
        const int row = y*128 + ncol + n*16 + (l & 15);
        const int idx = row*128 + (l >> 4)*8;
        bh[0][n] = *(const short8*)(wt1 + idx);
        bl[0][n] = *(const short8*)(wt1 + 32768 + idx);
    }

    // --- load x, cast to bf16 A tile, one-pass stats ---
    {
        const int r = tid >> 1, hf = tid & 1;
        const float* xr = x + (posBase + (long)r * stride) * 128 + hf * 64;
        float s = 0.f, ss = 0.f;
#pragma unroll
        for (int q = 0; q < 8; ++q) {
            const float4 a = ((const float4*)xr)[2*q];
            const float4 b = ((const float4*)xr)[2*q+1];
            s  += a.x + a.y + a.z + a.w + b.x + b.y + b.z + b.w;
            ss = fmaf(a.x,a.x, fmaf(a.y,a.y, fmaf(a.z,a.z, fmaf(a.w,a.w, ss))));
            ss = fmaf(b.x,b.x, fmaf(b.y,b.y, fmaf(b.z,b.z, fmaf(b.w,b.w, ss))));
            uint4 pk;
            pk.x = pkbf2(a.x, a.y); pk.y = pkbf2(a.z, a.w);
            pk.z = pkbf2(b.x, b.y); pk.w = pkbf2(b.z, b.w);
            const int col = (hf*128 + q*16) ^ ((r & 15) << 4);
            *(uint4*)(sbuf + r*256 + col) = pk;
        }
        s  += __shfl_xor(s, 1);
        ss += __shfl_xor(ss, 1);
        const float mu = s * (1.f/128.f);
        const float var = ss * (1.f/128.f) - mu*mu;
        const float rstd = rsqrtf(var + 1e-5f);
        if (hf == 0) {
            Ms[r] = mask[posBase + (long)r * stride];
            Mu[r] = mu; Rs[r] = rstd;
        }
    }
    __syncthreads();

    f32x4 acc[4][4];
#pragma unroll
    for (int m = 0; m < 4; ++m)
#pragma unroll
        for (int n = 0; n < 4; ++n) acc[m][n] = (f32x4){0.f,0.f,0.f,0.f};

#pragma unroll
    for (int step = 0; step < 4; ++step) {
        if (step < 3) {        // prefetch next step's B into the other set
            const int s1 = step + 1;
#pragma unroll
            for (int n = 0; n < 4; ++n) {
                const int row = y*128 + ncol + n*16 + (l & 15);
                const int idx = row*128 + s1*32 + (l >> 4)*8;
                bh[s1 & 1][n] = *(const short8*)(wt1 + idx);
                bl[s1 & 1][n] = *(const short8*)(wt1 + 32768 + idx);
            }
        }
        short8 ah[4];
#pragma unroll
        for (int m = 0; m < 4; ++m) {
            const int pos = mrow + m*16 + (l & 15);
            const int col = (step*64 + (l >> 4)*16) ^ ((pos & 15) << 4);
            ah[m] = *(const short8*)(sbuf + pos*256 + col);
        }
#pragma unroll
        for (int m = 0; m < 4; ++m) {
#pragma unroll
            for (int n = 0; n < 4; ++n) {
                acc[m][n] = __builtin_amdgcn_mfma_f32_16x16x32_bf16(ah[m], bh[step & 1][n], acc[m][n], 0, 0, 0);
                acc[m][n] = __builtin_amdgcn_mfma_f32_16x16x32_bf16(ah[m], bl[step & 1][n], acc[m][n], 0, 0, 0);
            }
        }
    }
    __syncthreads();   // A reads done; sbuf becomes G (u32-packed hi/lo)

    // --- LN-folded gate, all lanes active (j<8: e 0,1; j>=8: e 2,3) ---
    const int j = l & 15;
    const int e0 = (j >= 8) ? 2 : 0;
#pragma unroll
    for (int m = 0; m < 4; ++m) {
#pragma unroll
        for (int n = 0; n < 4; ++n) {
            const f32x4 a = acc[m][n];
            float pr[4];
#pragma unroll
            for (int e = 0; e < 4; ++e) pr[e] = __shfl_xor(a[e], 8);
            const int cl = (w >> 1)*32 + n*8 + (j & 7);
            const int och = o0 + cl;
            const float c1p = cb[och],       c2p = cb[128 + och];
            const float c1g = cb[256 + och], c2g = cb[384 + och];
            const int p0 = mrow + m*16 + (l >> 4)*4;
            uint2 pk;
#pragma unroll
            for (int t = 0; t < 2; ++t) {
                const int e = e0 + t;
                const float accP = (j >= 8) ? pr[e] : a[e];
                const float accG = (j >= 8) ? a[e] : pr[e];
                const float mu = Mu[p0+e], rstd = Rs[p0+e];
                const float p_ = fmaf(rstd, accP - mu*c1p, c2p);
                const float g_ = fmaf(rstd, accG - mu*c1g, c2g);
                const float g = p_ * sigmoidf_(g_) * Ms[p0+e];
                const ushort hi = bfbits(g);
                const ushort lo = bfbits(g - bf2f(hi));
                ((uint32*)&pk)[t] = ((uint32)hi << 16) | (uint32)lo;
            }
            *(uint2*)(sbuf + cl*512 + ((p0*4) ^ ((cl & 7) << 4)) + e0*4) = pk;
        }
    }
    __syncthreads();

    // --- cooperative plane stores: 256B-contiguous runs per plane ---
#pragma unroll
    for (int it = 0; it < 2; ++it) {
        const int u = it*256 + tid;
        const int c = u >> 3, seg = u & 7;
        ushort* hd = wsg + (long)(o0 + c) * NN + outBase + seg*16;
        ushort* ld = wsg + (long)(128 + o0 + c) * NN + outBase + seg*16;
#pragma unroll
        for (int half = 0; half < 2; ++half) {
            short8 hv, lv;
#pragma unroll
            for (int q = 0; q < 2; ++q) {
                const int b = seg*64 + half*32 + q*16;
                const uint4 w4 = *(const uint4*)(sbuf + c*512 + (b ^ ((c & 7) << 4)));
                hv[q*4+0] = (short)(w4.x >> 16); lv[q*4+0] = (short)(w4.x & 0xffffu);
                hv[q*4+1] = (short)(w4.y >> 16); lv[q*4+1] = (short)(w4.y & 0xffffu);
                hv[q*4+2] = (short)(w4.z >> 16); lv[q*4+2] = (short)(w4.z & 0xffffu);
                hv[q*4+3] = (short)(w4.w >> 16); lv[q*4+3] = (short)(w4.w & 0xffffu);
            }
            *(short8*)(hd + half*8) = hv;
            *(short8*)(ld + half*8) = lv;
        }
    }
}

// ---------------------------------------------------------------------------
// Triangular einsums: 64 NT-GEMMs, bf16 hi/lo (3 products), MFMA 16x16x32.
// NEW: 2-phase double-buffered pipeline — BK=32, two 32KiB LDS buffers;
// per step: STAGE(next buf) -> COMPUTE(cur) -> barrier (staging hides
// under the 48 MFMA).  Swizzle: 4-slot XOR (cs ^ (row&3)) on both sides.
// ---------------------------------------------------------------------------
__global__ __launch_bounds__(256, 2)
void k_einsum(const ushort* __restrict__ wsg, float* __restrict__ wst)
{
    const int bid = blockIdx.x;
    const int nb  = (bid & 7) * 128 + (bid >> 3);
    const int ch  = nb >> 4;
    const int bi  = (nb >> 2) & 3, bj = nb & 3;
    const int pch = (ch < 32) ? ch : ch + 32;

    const ushort* __restrict__ PH = wsg + (long)pch * NN;
    const ushort* __restrict__ PL = wsg + (long)(128 + pch) * NN;
    const ushort* __restrict__ QH = wsg + (long)(pch + 32) * NN;
    const ushort* __restrict__ QL = wsg + (long)(128 + pch + 32) * NN;
    float* __restrict__ T = wst + (long)ch * NN;

    __shared__ ushort smem[32768];   // 2 buffers x 32KiB (Ah,Al,Bh,Bl x 8KiB)

    const int tid = threadIdx.x;
    const int w = tid >> 6, l = tid & 63;

    // staging source offsets (pre-swizzled): chunk ci = w*128 + j*64 + lane
    int ebase[2];
#pragma unroll
    for (int jq = 0; jq < 2; ++jq) {
        const int ci  = w * 128 + jq * 64 + l;
        const int row = ci >> 2, cs = ci & 3;
        ebase[jq] = row * 512 + ((cs ^ (row & 3)) << 3);
    }
    const int aOff = bi * 128 * 512;
    const int bOff = bj * 128 * 512;

    f32x4 acc[4][4];
#pragma unroll
    for (int m = 0; m < 4; ++m)
#pragma unroll
        for (int n = 0; n < 4; ++n) acc[m][n] = (f32x4){0.f, 0.f, 0.f, 0.f};

    const int mrow = (w & 1) * 64;
    const int ncol = (w >> 1) * 64;

#define STAGE(buf, step)                                                          \
    {                                                                             \
        const int kOff = (step) * 32;                                             \
        _Pragma("unroll")                                                         \
        for (int jq = 0; jq < 2; ++jq) {                                          \
            char* dst = (char*)smem + (buf)*32768 + (w * 128 + jq * 64) * 16;     \
            __builtin_amdgcn_global_load_lds(                                     \
                (const __attribute__((address_space(1))) void*)(PH + aOff + ebase[jq] + kOff), \
                (__attribute__((address_space(3))) void*)(dst), 16, 0, 0);        \
            __builtin_amdgcn_global_load_lds(                                     \
                (const __attribute__((address_space(1))) void*)(PL + aOff + ebase[jq] + kOff), \
                (__attribute__((address_space(3))) void*)(dst + 8192), 16, 0, 0); \
            __builtin_amdgcn_global_load_lds(                                     \
                (const __attribute__((address_space(1))) void*)(QH + bOff + ebase[jq] + kOff), \
                (__attribute__((address_space(3))) void*)(dst + 16384), 16, 0, 0);\
            __builtin_amdgcn_global_load_lds(                                     \
                (const __attribute__((address_space(1))) void*)(QL + bOff + ebase[jq] + kOff), \
                (__attribute__((address_space(3))) void*)(dst + 24576), 16, 0, 0);\
        }                                                                         \
    }

    STAGE(0, 0);
    __syncthreads();   // implicit vmcnt(0) drain -> buf0 valid

    for (int t = 0; t < 16; ++t) {
        const int cur = t & 1;
        if (t < 15) STAGE(cur ^ 1, t + 1);   // issue next-tile loads first

        const char* sb = (const char*)smem + cur * 32768;
        short8 ah[4], al[4], bh[4], bl[4];
#pragma unroll
        for (int m = 0; m < 4; ++m) {
            const int r = mrow + m * 16 + (l & 15);
            const int off = r * 64 + ((((l >> 4)) ^ (r & 3)) << 4);
            ah[m] = *(const short8*)(sb + off);
            al[m] = *(const short8*)(sb + 8192 + off);
        }
#pragma unroll
        for (int n = 0; n < 4; ++n) {
            const int r = ncol + n * 16 + (l & 15);
            const int off = r * 64 + ((((l >> 4)) ^ (r & 3)) << 4);
            bh[n] = *(const short8*)(sb + 16384 + off);
            bl[n] = *(const short8*)(sb + 24576 + off);
        }
#pragma unroll
        for (int m = 0; m < 4; ++m) {
#pragma unroll
            for (int n = 0; n < 4; ++n) {
                acc[m][n] = __builtin_amdgcn_mfma_f32_16x16x32_bf16(ah[m], bh[n], acc[m][n], 0, 0, 0);
                acc[m][n] = __builtin_amdgcn_mfma_f32_16x16x32_bf16(ah[m], bl[n], acc[m][n], 0, 0, 0);
                acc[m][n] = __builtin_amdgcn_mfma_f32_16x16x32_bf16(al[m], bh[n], acc[m][n], 0, 0, 0);
            }
        }
        __syncthreads();   // drains next-stage vmcnt + protects cur for reuse
    }
#undef STAGE

    const int rbase = bi * 128 + mrow;
    const int cbase = bj * 128 + ncol;
#pragma unroll
    for (int m = 0; m < 4; ++m) {
#pragma unroll
        for (int n = 0; n < 4; ++n) {
#pragma unroll
            for (int r = 0; r < 4; ++r) {
                const int row = rbase + m * 16 + (l >> 4) * 4 + r;
                const int col = cbase + n * 16 + (l & 15);
                T[(long)row * NDIM + col] = acc[m][n][r];
            }
        }
    }
}

// ---------------------------------------------------------------------------
// Stage 2: gather t planes, LN2-folded dual GEMM (po,go), gate, mask -> out.
// B fragments for BOTH steps preloaded at kernel top (overlap gather/LN).
// ---------------------------------------------------------------------------
__global__ __launch_bounds__(256, 3)
void k_stage2(const float* __restrict__ wst, const float* __restrict__ mask,
              const ushort* __restrict__ wt2, const float* __restrict__ cb,
              float* __restrict__ out)
{
    __shared__ float tP[128][65];   // t gather; later reused as O[pos][ch]
    __shared__ char abuf[16384];    // A tile [128 pos][64 ch] bf16 swz
    __shared__ float Ms[128], Mu[128], Rs[128];

    const int tid = threadIdx.x;
    const long pos0 = (long)blockIdx.x * 128;
    const int y = blockIdx.y;
    const int o0 = y * 64;
    const int w = tid >> 6, l = tid & 63;
    const int mrow = (w & 1) * 64, ncol = (w >> 1) * 64;

    // --- preload both B steps (no LDS dependence) ---
    short8 bh[2][4], bl[2][4];
#pragma unroll
    for (int s = 0; s < 2; ++s)
#pragma unroll
        for (int n = 0; n < 4; ++n) {
            const int row = y*128 + ncol + n*16 + (l & 15);
            const int idx = row*64 + s*32 + (l >> 4)*8;
            bh[s][n] = *(const short8*)(wt2 + idx);
            bl[s][n] = *(const short8*)(wt2 + 16384 + idx);
        }

#pragma unroll
    for (int q = 0; q < 8; ++q) {
        const int u = q*256 + tid, d = u >> 5, p4 = u & 31;
        const float4 v = *(const float4*)(wst + (long)d * NN + pos0 + p4*4);
        tP[p4*4+0][d] = v.x; tP[p4*4+1][d] = v.y;
        tP[p4*4+2][d] = v.z; tP[p4*4+3][d] = v.w;
    }
    if (tid < 128) Ms[tid] = mask[pos0 + tid];
    __syncthreads();

    // stats + direct bf16 cast (LN folded into epilogue)
    {
        const int r = tid >> 1, hf = tid & 1;
        float v[32]; float s = 0.f, ss = 0.f;
#pragma unroll
        for (int jz = 0; jz < 32; ++jz) {
            v[jz] = tP[r][hf*32+jz];
            s += v[jz]; ss = fmaf(v[jz], v[jz], ss);
        }
        s  += __shfl_xor(s, 1);
        ss += __shfl_xor(ss, 1);
        const float mu = s * (1.f/64.f);
        const float var = ss * (1.f/64.f) - mu*mu;
        const float rstd = rsqrtf(var + 1e-5f);
        if (hf == 0) { Mu[r] = mu; Rs[r] = rstd; }
#pragma unroll
        for (int jj = 0; jj < 4; ++jj) {
            uint4 pk;
            pk.x = pkbf2(v[jj*8+0], v[jj*8+1]); pk.y = pkbf2(v[jj*8+2], v[jj*8+3]);
            pk.z = pkbf2(v[jj*8+4], v[jj*8+5]); pk.w = pkbf2(v[jj*8+6], v[jj*8+7]);
            const int col = (hf*64 + jj*16) ^ ((r & 7) << 4);
            *(uint4*)(abuf + r*128 + col) = pk;
        }
    }
    __syncthreads();

    f32x4 acc[4][4];
#pragma unroll
    for (int m = 0; m < 4; ++m)
#pragma unroll
        for (int n = 0; n < 4; ++n) acc[m][n] = (f32x4){0.f,0.f,0.f,0.f};

#pragma unroll
    for (int step = 0; step < 2; ++step) {
        short8 ah[4];
#pragma unroll
        for (int m = 0; m < 4; ++m) {
            const int pos = mrow + m*16 + (l & 15);
            const int col = (step*64 + (l >> 4)*16) ^ ((pos & 7) << 4);
            ah[m] = *(const short8*)(abuf + pos*128 + col);
        }
#pragma unroll
        for (int m = 0; m < 4; ++m) {
#pragma unroll
            for (int n = 0; n < 4; ++n) {
                acc[m][n] = __builtin_amdgcn_mfma_f32_16x16x32_bf16(ah[m], bh[step][n], acc[m][n], 0, 0, 0);
                acc[m][n] = __builtin_amdgcn_mfma_f32_16x16x32_bf16(ah[m], bl[step][n], acc[m][n], 0, 0, 0);
            }
        }
    }

    // LN-folded gate, all lanes active; O[pos][ch] into tP
    const int j = l & 15;
    const int e0 = (j >= 8) ? 2 : 0;
#pragma unroll
    for (int m = 0; m < 4; ++m) {
#pragma unroll
        for (int n = 0; n < 4; ++n) {
            const f32x4 a = acc[m][n];
            float pr[4];
#pragma unroll
            for (int e = 0; e < 4; ++e) pr[e] = __shfl_xor(a[e], 8);
            const int cl = (w >> 1)*32 + n*8 + (j & 7);
            const int och = o0 + cl;
            const float c1p = cb[och],       c2p = cb[128 + och];
            const float c1g = cb[256 + och], c2g = cb[384 + och];
            const int p0 = mrow + m*16 + (l >> 4)*4;
#pragma unroll
            for (int t = 0; t < 2; ++t) {
                const int e = e0 + t;
                const float accP = (j >= 8) ? pr[e] : a[e];
                const float accG = (j >= 8) ? a[e] : pr[e];
                const float mu = Mu[p0+e], rstd = Rs[p0+e];
                const float p_ = fmaf(rstd, accP - mu*c1p, c2p);
                const float g_ = fmaf(rstd, accG - mu*c1g, c2g);
                tP[p0 + e][cl] = p_ * sigmoidf_(g_) * Ms[p0+e];
            }
        }
    }
    __syncthreads();

    // cooperative output stores
    {
        const int r2 = tid >> 1, h2 = tid & 1;
        float* op = out + (pos0 + r2)*128 + o0 + h2*32;
#pragma unroll
        for (int i = 0; i < 8; ++i) {
            float4 v;
            v.x = tP[r2][h2*32 + i*4 + 0];
            v.y = tP[r2][h2*32 + i*4 + 1];
            v.z = tP[r2][h2*32 + i*4 + 2];
            v.w = tP[r2][h2*32 + i*4 + 3];
            *(float4*)(op + i*4) = v;
        }
    }
}

// ---------------------------------------------------------------------------
extern "C" void kernel_launch(void* const* d_in, const int* in_sizes, int n_in,
                              void* d_out, int out_size, void* d_ws, size_t ws_size,
                              hipStream_t stream)
{
    const float* x     = (const float*)d_in[0];
    const float* mask  = (const float*)d_in[1];
    const float* ln1_w = (const float*)d_in[2];
    const float* ln1_b = (const float*)d_in[3];
    const float* pi_w  = (const float*)d_in[4];
    const float* pi_b  = (const float*)d_in[5];
    const float* gi_w  = (const float*)d_in[6];
    const float* gi_b  = (const float*)d_in[7];
    const float* ln2_w = (const float*)d_in[8];
    const float* ln2_b = (const float*)d_in[9];
    const float* po_w  = (const float*)d_in[10];
    const float* po_b  = (const float*)d_in[11];
    const float* go_w  = (const float*)d_in[12];
    const float* go_b  = (const float*)d_in[13];

    ushort* wsg = (ushort*)d_ws;                              // 256 bf16 planes
    float* wst = (float*)((char*)d_ws + (long)256 * NN * 2);  // 64 fp32 planes
    ushort* wt1 = (ushort*)wst;                               // 128 KiB transient
    float*  cb1 = (float*)(wt1 + 65536);                      // 2 KiB
    ushort* wt2 = wsg;                                        // 64 KiB transient
    float*  cb2 = (float*)(wt2 + 32768);                      // 2 KiB

    k_prep<<<64, 256, 0, stream>>>(pi_w, gi_w, ln1_w, 128, wt1);
    k_csum<<<2, 256, 0, stream>>>(pi_w, gi_w, ln1_w, ln1_b, pi_b, gi_b, 128, cb1);
    k_stage1<<<dim3(2048, 2), 256, 0, stream>>>(x, mask, wt1, cb1, wsg);
    k_einsum<<<1024, 256, 0, stream>>>(wsg, wst);
    k_prep<<<32, 256, 0, stream>>>(po_w, go_w, ln2_w, 64, wt2);
    k_csum<<<2, 256, 0, stream>>>(po_w, go_w, ln2_w, ln2_b, po_b, go_b, 64, cb2);
    k_stage2<<<dim3(2048, 2), 256, 0, stream>>>(wst, mask, wt2, cb2, (float*)d_out);
}

// Round 10
// 383.361 us; speedup vs baseline: 1.1114x; 1.0183x over previous
//
#include <hip/hip_runtime.h>
#include <hip/hip_bf16.h>

#define NDIM 512
#define NN   (NDIM * NDIM)

// Workspace:
//   bf16 planes 0..127   : g hi, channel c.  c<64: [i][k]=g[i][k][c]; c>=64: [i][k]=g[k][i][c]
//   bf16 planes 128..255 : g lo, same indexing.              (128 MiB)
//   fp32 planes @ 256*NN*2 B: t[dd][i][j], 64 planes          (64 MiB)
// Transient: wt1+cb1 at wst start (einsum overwrites later);
//            wt2+cb2 at wsg start (written after einsum consumes g).
// LN folded into GEMMs: out = rstd*(acc - mu*c1) + c2, W' = ln_w*W.

using short8 = __attribute__((ext_vector_type(8))) short;
using f32x4  = __attribute__((ext_vector_type(4))) float;
typedef unsigned int uint32;
typedef unsigned short ushort;

__device__ __forceinline__ float sigmoidf_(float z) { return 1.f / (1.f + __expf(-z)); }
__device__ __forceinline__ uint32 pkbf2(float a, float b) {
    __hip_bfloat162 h = __float22bfloat162_rn(float2{a, b});
    uint32 u; __builtin_memcpy(&u, &h, 4); return u;
}
__device__ __forceinline__ ushort bfbits(float f) {
    __hip_bfloat16 h = __float2bfloat16(f);
    ushort u; __builtin_memcpy(&u, &h, 2); return u;
}
__device__ __forceinline__ float bf2f(ushort h) {
    return __uint_as_float(((uint32)h) << 16);
}

// ---------------------------------------------------------------------------
// Weight prep: W'[k][o] = ln_w[k]*W[k][o], bf16 hi/lo, rows interleaved in
// 16-groups (s<8: P ch 8q+s, s>=8: G ch 8q+s-8). hi[(h*128+row)*K+k], lo +256*K.
// ---------------------------------------------------------------------------
__global__ void k_prep(const float* __restrict__ Wp, const float* __restrict__ Wg,
                       const float* __restrict__ lnw, int K,
                       ushort* __restrict__ dst)
{
    const int idx = blockIdx.x * 256 + threadIdx.x;   // 0 .. K*128-1
    const int k = idx >> 7, o = idx & 127;
    const int h = o >> 6, cl = o & 63;
    const int q = cl >> 3, s7 = cl & 7;
    const float wk = lnw[k];
    const float vp = Wp[k * 128 + o] * wk;
    const float vg = Wg[k * 128 + o] * wk;
    const int rowp = (q << 4) + s7;
    const int rowg = (q << 4) + 8 + s7;
    ushort hi;
    hi = bfbits(vp);
    dst[(h * 128 + rowp) * K + k] = hi;
    dst[256 * K + (h * 128 + rowp) * K + k] = bfbits(vp - bf2f(hi));
    hi = bfbits(vg);
    dst[(h * 128 + rowg) * K + k] = hi;
    dst[256 * K + (h * 128 + rowg) * K + k] = bfbits(vg - bf2f(hi));
}

// cb: [0..127]=c1P, [128..255]=c2P+biasP, [256..383]=c1G, [384..511]=c2G+biasG
__global__ void k_csum(const float* __restrict__ Wp, const float* __restrict__ Wg,
                       const float* __restrict__ lnw, const float* __restrict__ lnb,
                       const float* __restrict__ bp, const float* __restrict__ bg,
                       int K, float* __restrict__ cb)
{
    __shared__ float red[2][2][128];
    const int b = blockIdx.x;
    const float* W = b ? Wg : Wp;
    const float* bias = b ? bg : bp;
    const int tid = threadIdx.x;
    const int o = tid & 127, kh = tid >> 7;
    const int kham = K >> 1;
    const int k0 = kh * kham;
    float c1 = 0.f, c2 = 0.f;
#pragma unroll 8
    for (int k = 0; k < kham; ++k) {
        const float wv = W[(k0 + k) * 128 + o];
        c1 = fmaf(lnw[k0 + k], wv, c1);
        c2 = fmaf(lnb[k0 + k], wv, c2);
    }
    red[kh][0][o] = c1; red[kh][1][o] = c2;
    __syncthreads();
    if (kh == 0) {
        const int base = b ? 256 : 0;
        cb[base + o] = red[0][0][o] + red[1][0][o];
        cb[base + 128 + o] = red[0][1][o] + red[1][1][o] + bias[o];
    }
}

// ---------------------------------------------------------------------------
// Stage 1: cast-x GEMM (pi,gi interleaved), LN folded into epilogue.
// ---------------------------------------------------------------------------
__global__ __launch_bounds__(256, 4)
void k_stage1(const float* __restrict__ x, const float* __restrict__ mask,
              const ushort* __restrict__ wt1, const float* __restrict__ cb,
              ushort* __restrict__ wsg)
{
    __shared__ char sbuf[32768];   // A tile bf16(x) swz; later G u32-packed
    __shared__ float Ms[128], Mu[128], Rs[128];

    const int tid = threadIdx.x;
    const int bx = blockIdx.x;
    const int y  = blockIdx.y;
    const int o0 = y * 64;
    const int w = tid >> 6, l = tid & 63;
    const int mrow = (w & 1) * 64, ncol = (w >> 1) * 64;

    long posBase, outBase; int stride;
    if (y == 0) {
        posBase = ((long)(bx >> 2)) * 512 + (long)(bx & 3) * 128;
        outBase = posBase; stride = 1;
    } else {
        posBase = ((long)(bx >> 9)) * 65536 + (bx & 511);
        outBase = (long)(bx & 511) * 512 + ((bx >> 9) * 128);
        stride = 512;
    }

    // --- B prefetch for step 0 (overlaps x-load/LN) ---
    short8 bh[2][4], bl[2][4];
#pragma unroll
    for (int n = 0; n < 4; ++n) {
        const int row = y*128 + ncol + n*16 + (l & 15);
        const int idx = row*128 + (l >> 4)*8;
        bh[0][n] = *(const short8*)(wt1 + idx);
        bl[0][n] = *(const short8*)(wt1 + 32768 + idx);
    }

    // --- load x, cast to bf16 A tile, one-pass stats ---
    {
        const int r = tid >> 1, hf = tid & 1;
        const float* xr = x + (posBase + (long)r * stride) * 128 + hf * 64;
        float s = 0.f, ss = 0.f;
#pragma unroll
        for (int q = 0; q < 8; ++q) {
            const float4 a = ((const float4*)xr)[2*q];
            const float4 b = ((const float4*)xr)[2*q+1];
            s  += a.x + a.y + a.z + a.w + b.x + b.y + b.z + b.w;
            ss = fmaf(a.x,a.x, fmaf(a.y,a.y, fmaf(a.z,a.z, fmaf(a.w,a.w, ss))));
            ss = fmaf(b.x,b.x, fmaf(b.y,b.y, fmaf(b.z,b.z, fmaf(b.w,b.w, ss))));
            uint4 pk;
            pk.x = pkbf2(a.x, a.y); pk.y = pkbf2(a.z, a.w);
            pk.z = pkbf2(b.x, b.y); pk.w = pkbf2(b.z, b.w);
            const int col = (hf*128 + q*16) ^ ((r & 15) << 4);
            *(uint4*)(sbuf + r*256 + col) = pk;
        }
        s  += __shfl_xor(s, 1);
        ss += __shfl_xor(ss, 1);
        const float mu = s * (1.f/128.f);
        const float var = ss * (1.f/128.f) - mu*mu;
        const float rstd = rsqrtf(var + 1e-5f);
        if (hf == 0) {
            Ms[r] = mask[posBase + (long)r * stride];
            Mu[r] = mu; Rs[r] = rstd;
        }
    }
    __syncthreads();

    f32x4 acc[4][4];
#pragma unroll
    for (int m = 0; m < 4; ++m)
#pragma unroll
        for (int n = 0; n < 4; ++n) acc[m][n] = (f32x4){0.f,0.f,0.f,0.f};

#pragma unroll
    for (int step = 0; step < 4; ++step) {
        if (step < 3) {
            const int s1 = step + 1;
#pragma unroll
            for (int n = 0; n < 4; ++n) {
                const int row = y*128 + ncol + n*16 + (l & 15);
                const int idx = row*128 + s1*32 + (l >> 4)*8;
                bh[s1 & 1][n] = *(const short8*)(wt1 + idx);
                bl[s1 & 1][n] = *(const short8*)(wt1 + 32768 + idx);
            }
        }
        short8 ah[4];
#pragma unroll
        for (int m = 0; m < 4; ++m) {
            const int pos = mrow + m*16 + (l & 15);
            const int col = (step*64 + (l >> 4)*16) ^ ((pos & 15) << 4);
            ah[m] = *(const short8*)(sbuf + pos*256 + col);
        }
#pragma unroll
        for (int m = 0; m < 4; ++m) {
#pragma unroll
            for (int n = 0; n < 4; ++n) {
                acc[m][n] = __builtin_amdgcn_mfma_f32_16x16x32_bf16(ah[m], bh[step & 1][n], acc[m][n], 0, 0, 0);
                acc[m][n] = __builtin_amdgcn_mfma_f32_16x16x32_bf16(ah[m], bl[step & 1][n], acc[m][n], 0, 0, 0);
            }
        }
    }
    __syncthreads();   // A reads done; sbuf becomes G (u32-packed hi/lo)

    // --- LN-folded gate, all lanes active ---
    const int j = l & 15;
    const int e0 = (j >= 8) ? 2 : 0;
#pragma unroll
    for (int m = 0; m < 4; ++m) {
#pragma unroll
        for (int n = 0; n < 4; ++n) {
            const f32x4 a = acc[m][n];
            float pr[4];
#pragma unroll
            for (int e = 0; e < 4; ++e) pr[e] = __shfl_xor(a[e], 8);
            const int cl = (w >> 1)*32 + n*8 + (j & 7);
            const int och = o0 + cl;
            const float c1p = cb[och],       c2p = cb[128 + och];
            const float c1g = cb[256 + och], c2g = cb[384 + och];
            const int p0 = mrow + m*16 + (l >> 4)*4;
            uint2 pk;
#pragma unroll
            for (int t = 0; t < 2; ++t) {
                const int e = e0 + t;
                const float accP = (j >= 8) ? pr[e] : a[e];
                const float accG = (j >= 8) ? a[e] : pr[e];
                const float mu = Mu[p0+e], rstd = Rs[p0+e];
                const float p_ = fmaf(rstd, accP - mu*c1p, c2p);
                const float g_ = fmaf(rstd, accG - mu*c1g, c2g);
                const float g = p_ * sigmoidf_(g_) * Ms[p0+e];
                const ushort hi = bfbits(g);
                const ushort lo = bfbits(g - bf2f(hi));
                ((uint32*)&pk)[t] = ((uint32)hi << 16) | (uint32)lo;
            }
            *(uint2*)(sbuf + cl*512 + ((p0*4) ^ ((cl & 7) << 4)) + e0*4) = pk;
        }
    }
    __syncthreads();

    // --- cooperative plane stores ---
#pragma unroll
    for (int it = 0; it < 2; ++it) {
        const int u = it*256 + tid;
        const int c = u >> 3, seg = u & 7;
        ushort* hd = wsg + (long)(o0 + c) * NN + outBase + seg*16;
        ushort* ld = wsg + (long)(128 + o0 + c) * NN + outBase + seg*16;
#pragma unroll
        for (int half = 0; half < 2; ++half) {
            short8 hv, lv;
#pragma unroll
            for (int q = 0; q < 2; ++q) {
                const int b = seg*64 + half*32 + q*16;
                const uint4 w4 = *(const uint4*)(sbuf + c*512 + (b ^ ((c & 7) << 4)));
                hv[q*4+0] = (short)(w4.x >> 16); lv[q*4+0] = (short)(w4.x & 0xffffu);
                hv[q*4+1] = (short)(w4.y >> 16); lv[q*4+1] = (short)(w4.y & 0xffffu);
                hv[q*4+2] = (short)(w4.z >> 16); lv[q*4+2] = (short)(w4.z & 0xffffu);
                hv[q*4+3] = (short)(w4.w >> 16); lv[q*4+3] = (short)(w4.w & 0xffffu);
            }
            *(short8*)(hd + half*8) = hv;
            *(short8*)(ld + half*8) = lv;
        }
    }
}

// ---------------------------------------------------------------------------
// Triangular einsums: 64 NT-GEMMs, bf16 hi/lo (3 products), MFMA 16x16x32.
// 256x256 tile, 512 threads / 8 waves (4M x 2N, 64x128 per wave), BK=32,
// double-buffered 128 KiB LDS.  LDS row = 128 B: [hi c0..3 | lo c0..3],
// slot = chunk ^ (row&7) (same involution pre-applied on the staging source).
// Waves 0-3 stage A, 4-7 stage B; linear 1 KiB/wave-load dests.
// XCD-chunked: the 4 tiles of one channel land on one XCD (panel L2 reuse).
// ---------------------------------------------------------------------------
__global__ __launch_bounds__(512, 1)
void k_einsum(const ushort* __restrict__ wsg, float* __restrict__ wst)
{
    const int bid = blockIdx.x;                  // 0..255
    const int nb  = (bid & 7) * 32 + (bid >> 3); // channel = nb>>2 on XCD bid&7
    const int ch  = nb >> 2;
    const int bi  = (nb >> 1) & 1, bj = nb & 1;
    const int pch = (ch < 32) ? ch : ch + 32;

    const ushort* __restrict__ PH = wsg + (long)pch * NN;
    const ushort* __restrict__ QH = wsg + (long)(pch + 32) * NN;
    float* __restrict__ T = wst + (long)ch * NN;

    __shared__ char smem[131072];   // 2 buf x (A 32K | B 32K)

    const int tid = threadIdx.x;
    const int w = tid >> 6, l = tid & 63;
    const int isB = w >> 2;

    // staging source offsets (elements), 8 wave-loads per wave per buffer
    const ushort* sbase = isB ? (QH + (long)bj * 131072) : (PH + (long)bi * 131072);
    int soff[8];
#pragma unroll
    for (int i = 0; i < 8; ++i) {
        const int ci  = ((w & 3) * 8 + i) * 64 + l;       // 0..2047 within matrix
        const int row = ci >> 3, s = ci & 7;
        const int c   = s ^ (row & 7);                    // c<4: hi chunk c; c>=4: lo chunk c-4
        soff[i] = row * 512 + (c >> 2) * (128 * NN) + (c & 3) * 8;
    }
    const int dbase = isB * 32768 + (w & 3) * 8192;       // + i*1024 per wave-load

    f32x4 acc[4][8];
#pragma unroll
    for (int m = 0; m < 4; ++m)
#pragma unroll
        for (int n = 0; n < 8; ++n) acc[m][n] = (f32x4){0.f, 0.f, 0.f, 0.f};

    const int wr = w >> 1;          // 0..3 : row quadrant (64 rows)
    const int wc = w & 1;           // 0..1 : col half (128 cols)

#define STAGE(buf, step)                                                           \
    {                                                                              \
        const int kOff = (step) * 32;                                              \
        _Pragma("unroll")                                                          \
        for (int i = 0; i < 8; ++i) {                                              \
            __builtin_amdgcn_global_load_lds(                                      \
                (const __attribute__((address_space(1))) void*)(sbase + soff[i] + kOff), \
                (__attribute__((address_space(3))) void*)(smem + (buf)*65536 + dbase + i*1024), \
                16, 0, 0);                                                         \
        }                                                                          \
    }

    STAGE(0, 0);
    __syncthreads();

    for (int t = 0; t < 16; ++t) {
        const int cur = t & 1;
        if (t < 15) STAGE(cur ^ 1, t + 1);

        const char* sA = (const char*)smem + cur * 65536;
        const char* sB = sA + 32768;
        const int jc = l >> 4;                 // k-chunk 0..3
        short8 ah[4], al[4];
#pragma unroll
        for (int m = 0; m < 4; ++m) {
            const int r = wr * 64 + m * 16 + (l & 15);
            ah[m] = *(const short8*)(sA + r * 128 + ((jc       ^ (r & 7)) << 4));
            al[m] = *(const short8*)(sA + r * 128 + (((jc | 4) ^ (r & 7)) << 4));
        }
#pragma unroll
        for (int n = 0; n < 8; ++n) {
            const int r = wc * 128 + n * 16 + (l & 15);
            const short8 bh = *(const short8*)(sB + r * 128 + ((jc       ^ (r & 7)) << 4));
            const short8 bl = *(const short8*)(sB + r * 128 + (((jc | 4) ^ (r & 7)) << 4));
#pragma unroll
            for (int m = 0; m < 4; ++m) {
                acc[m][n] = __builtin_amdgcn_mfma_f32_16x16x32_bf16(ah[m], bh, acc[m][n], 0, 0, 0);
                acc[m][n] = __builtin_amdgcn_mfma_f32_16x16x32_bf16(ah[m], bl, acc[m][n], 0, 0, 0);
                acc[m][n] = __builtin_amdgcn_mfma_f32_16x16x32_bf16(al[m], bh, acc[m][n], 0, 0, 0);
            }
        }
        __syncthreads();
    }
#undef STAGE

    const int rbase = bi * 256 + wr * 64;
    const int cbase = bj * 256 + wc * 128;
#pragma unroll
    for (int m = 0; m < 4; ++m) {
#pragma unroll
        for (int n = 0; n < 8; ++n) {
#pragma unroll
            for (int r = 0; r < 4; ++r) {
                const int row = rbase + m * 16 + (l >> 4) * 4 + r;
                const int col = cbase + n * 16 + (l & 15);
                T[(long)row * NDIM + col] = acc[m][n][r];
            }
        }
    }
}

// ---------------------------------------------------------------------------
// Stage 2: gather t planes, LN2-folded dual GEMM (po,go), gate, mask -> out.
// ---------------------------------------------------------------------------
__global__ __launch_bounds__(256, 3)
void k_stage2(const float* __restrict__ wst, const float* __restrict__ mask,
              const ushort* __restrict__ wt2, const float* __restrict__ cb,
              float* __restrict__ out)
{
    __shared__ float tP[128][65];
    __shared__ char abuf[16384];
    __shared__ float Ms[128], Mu[128], Rs[128];

    const int tid = threadIdx.x;
    const long pos0 = (long)blockIdx.x * 128;
    const int y = blockIdx.y;
    const int o0 = y * 64;
    const int w = tid >> 6, l = tid & 63;
    const int mrow = (w & 1) * 64, ncol = (w >> 1) * 64;

    short8 bh[2][4], bl[2][4];
#pragma unroll
    for (int s = 0; s < 2; ++s)
#pragma unroll
        for (int n = 0; n < 4; ++n) {
            const int row = y*128 + ncol + n*16 + (l & 15);
            const int idx = row*64 + s*32 + (l >> 4)*8;
            bh[s][n] = *(const short8*)(wt2 + idx);
            bl[s][n] = *(const short8*)(wt2 + 16384 + idx);
        }

#pragma unroll
    for (int q = 0; q < 8; ++q) {
        const int u = q*256 + tid, d = u >> 5, p4 = u & 31;
        const float4 v = *(const float4*)(wst + (long)d * NN + pos0 + p4*4);
        tP[p4*4+0][d] = v.x; tP[p4*4+1][d] = v.y;
        tP[p4*4+2][d] = v.z; tP[p4*4+3][d] = v.w;
    }
    if (tid < 128) Ms[tid] = mask[pos0 + tid];
    __syncthreads();

    {
        const int r = tid >> 1, hf = tid & 1;
        float v[32]; float s = 0.f, ss = 0.f;
#pragma unroll
        for (int jz = 0; jz < 32; ++jz) {
            v[jz] = tP[r][hf*32+jz];
            s += v[jz]; ss = fmaf(v[jz], v[jz], ss);
        }
        s  += __shfl_xor(s, 1);
        ss += __shfl_xor(ss, 1);
        const float mu = s * (1.f/64.f);
        const float var = ss * (1.f/64.f) - mu*mu;
        const float rstd = rsqrtf(var + 1e-5f);
        if (hf == 0) { Mu[r] = mu; Rs[r] = rstd; }
#pragma unroll
        for (int jj = 0; jj < 4; ++jj) {
            uint4 pk;
            pk.x = pkbf2(v[jj*8+0], v[jj*8+1]); pk.y = pkbf2(v[jj*8+2], v[jj*8+3]);
            pk.z = pkbf2(v[jj*8+4], v[jj*8+5]); pk.w = pkbf2(v[jj*8+6], v[jj*8+7]);
            const int col = (hf*64 + jj*16) ^ ((r & 7) << 4);
            *(uint4*)(abuf + r*128 + col) = pk;
        }
    }
    __syncthreads();

    f32x4 acc[4][4];
#pragma unroll
    for (int m = 0; m < 4; ++m)
#pragma unroll
        for (int n = 0; n < 4; ++n) acc[m][n] = (f32x4){0.f,0.f,0.f,0.f};

#pragma unroll
    for (int step = 0; step < 2; ++step) {
        short8 ah[4];
#pragma unroll
        for (int m = 0; m < 4; ++m) {
            const int pos = mrow + m*16 + (l & 15);
            const int col = (step*64 + (l >> 4)*16) ^ ((pos & 7) << 4);
            ah[m] = *(const short8*)(abuf + pos*128 + col);
        }
#pragma unroll
        for (int m = 0; m < 4; ++m) {
#pragma unroll
            for (int n = 0; n < 4; ++n) {
                acc[m][n] = __builtin_amdgcn_mfma_f32_16x16x32_bf16(ah[m], bh[step][n], acc[m][n], 0, 0, 0);
                acc[m][n] = __builtin_amdgcn_mfma_f32_16x16x32_bf16(ah[m], bl[step][n], acc[m][n], 0, 0, 0);
            }
        }
    }

    const int j = l & 15;
    const int e0 = (j >= 8) ? 2 : 0;
#pragma unroll
    for (int m = 0; m < 4; ++m) {
#pragma unroll
        for (int n = 0; n < 4; ++n) {
            const f32x4 a = acc[m][n];
            float pr[4];
#pragma unroll
            for (int e = 0; e < 4; ++e) pr[e] = __shfl_xor(a[e], 8);
            const int cl = (w >> 1)*32 + n*8 + (j & 7);
            const int och = o0 + cl;
            const float c1p = cb[och],       c2p = cb[128 + och];
            const float c1g = cb[256 + och], c2g = cb[384 + och];
            const int p0 = mrow + m*16 + (l >> 4)*4;
#pragma unroll
            for (int t = 0; t < 2; ++t) {
                const int e = e0 + t;
                const float accP = (j >= 8) ? pr[e] : a[e];
                const float accG = (j >= 8) ? a[e] : pr[e];
                const float mu = Mu[p0+e], rstd = Rs[p0+e];
                const float p_ = fmaf(rstd, accP - mu*c1p, c2p);
                const float g_ = fmaf(rstd, accG - mu*c1g, c2g);
                tP[p0 + e][cl] = p_ * sigmoidf_(g_) * Ms[p0+e];
            }
        }
    }
    __syncthreads();

    {
        const int r2 = tid >> 1, h2 = tid & 1;
        float* op = out + (pos0 + r2)*128 + o0 + h2*32;
#pragma unroll
        for (int i = 0; i < 8; ++i) {
            float4 v;
            v.x = tP[r2][h2*32 + i*4 + 0];
            v.y = tP[r2][h2*32 + i*4 + 1];
            v.z = tP[r2][h2*32 + i*4 + 2];
            v.w = tP[r2][h2*32 + i*4 + 3];
            *(float4*)(op + i*4) = v;
        }
    }
}

// ---------------------------------------------------------------------------
extern "C" void kernel_launch(void* const* d_in, const int* in_sizes, int n_in,
                              void* d_out, int out_size, void* d_ws, size_t ws_size,
                              hipStream_t stream)
{
    const float* x     = (const float*)d_in[0];
    const float* mask  = (const float*)d_in[1];
    const float* ln1_w = (const float*)d_in[2];
    const float* ln1_b = (const float*)d_in[3];
    const float* pi_w  = (const float*)d_in[4];
    const float* pi_b  = (const float*)d_in[5];
    const float* gi_w  = (const float*)d_in[6];
    const float* gi_b  = (const float*)d_in[7];
    const float* ln2_w = (const float*)d_in[8];
    const float* ln2_b = (const float*)d_in[9];
    const float* po_w  = (const float*)d_in[10];
    const float* po_b  = (const float*)d_in[11];
    const float* go_w  = (const float*)d_in[12];
    const float* go_b  = (const float*)d_in[13];

    ushort* wsg = (ushort*)d_ws;                              // 256 bf16 planes
    float* wst = (float*)((char*)d_ws + (long)256 * NN * 2);  // 64 fp32 planes
    ushort* wt1 = (ushort*)wst;                               // 128 KiB transient
    float*  cb1 = (float*)(wt1 + 65536);                      // 2 KiB
    ushort* wt2 = wsg;                                        // 64 KiB transient
    float*  cb2 = (float*)(wt2 + 32768);                      // 2 KiB

    k_prep<<<64, 256, 0, stream>>>(pi_w, gi_w, ln1_w, 128, wt1);
    k_csum<<<2, 256, 0, stream>>>(pi_w, gi_w, ln1_w, ln1_b, pi_b, gi_b, 128, cb1);
    k_stage1<<<dim3(2048, 2), 256, 0, stream>>>(x, mask, wt1, cb1, wsg);
    k_einsum<<<256, 512, 0, stream>>>(wsg, wst);
    k_prep<<<32, 256, 0, stream>>>(po_w, go_w, ln2_w, 64, wt2);
    k_csum<<<2, 256, 0, stream>>>(po_w, go_w, ln2_w, ln2_b, po_b, go_b, 64, cb2);
    k_stage2<<<dim3(2048, 2), 256, 0, stream>>>(wst, mask, wt2, cb2, (float*)d_out);
}